// Round 1
// baseline (105.591 us; speedup 1.0000x reference)
//
#include <hip/hip_runtime.h>
#include <math.h>

// DILATE / soft-DTW — round 13: 2-problem ILP per thread (TLP->ILP trade).
// r12 counters: VALUBusy 31%, wall ~300 cyc/step vs ~120 issue -> latency-bound
// on the serial softmin chain with ~0.9 active waves/SIMD. Fix: each block now
// owns TWO problems (2k, 2k+1); every thread carries both DP states in
// registers and the inner step interleaves the two independent chains, so one
// chain's exp2/log2 latency is hidden under the other's issue.
//  - Grid 256 x 192 (1 block/CU, 3 waves). VGPR headroom is huge (was 36).
//  - MERGED float4 ring: bRG[w][slot] = (rC2_A, rdot_A, rC2_B, rdot_B);
//    one ds_write_b128 publish/step, window = 18 aligned b128 broadcast reads.
//  - Omega (j-i)^2 is shared between the two problems (same row/diag).
//  - Per-problem op order is bit-identical to r12 -> absmax stays 0.
// Kept from r12: C2-domain carry (rC2 = fma(dtS,dtS,mnC2) - log2(ss), exact
// since GLN2*C2 == 1; subtract-form exp args mandatory), DPP old-injection
// (lane0 <- ring slot d via bound_ctrl=false), chunk skip, lgkm-only barrier,
// forward-mode AD, unwritten-ring-slot = (BIGC2, 0) true-border semantics.

#define NN     160
#define BC_TOT 512
#define B_SZ   64
#define C_SZ   8
#define BIGC2  1e12f              // border sentinel in C2 domain
#define SC2    12.01122405f       // sqrt(C2), C2 = 144.269504089
#define GLN2   0.0069314718056f   // gamma*ln2 == 1/C2
#define KPH    16
#define NCHUNK 20                 // 320 diag-steps (incl. 1 pad)
#define NPHASE 22                 // NCHUNK + 2 pipeline fill
#define RSZ    328                // linear ring slots (reads up to 321)

__device__ __forceinline__ float fexp2(float x) {
#if __has_builtin(__builtin_amdgcn_exp2f)
    return __builtin_amdgcn_exp2f(x);
#else
    return exp2f(x);
#endif
}
__device__ __forceinline__ float flog2(float x) {
#if __has_builtin(__builtin_amdgcn_logf)
    return __builtin_amdgcn_logf(x);
#else
    return log2f(x);
#endif
}
__device__ __forceinline__ float frcp(float x) {
#if __has_builtin(__builtin_amdgcn_rcpf)
    return __builtin_amdgcn_rcpf(x);
#else
    return 1.0f / x;
#endif
}
// lane i <- lane i-1; lane 0 <- old (bound_ctrl=false). Standard scan idiom.
__device__ __forceinline__ float dpp_up1_inj(float old, float x) {
    int oi = __builtin_bit_cast(int, old);
    int xi = __builtin_bit_cast(int, x);
    return __builtin_bit_cast(float,
        __builtin_amdgcn_update_dpp(oi, xi, 0x138, 0xF, 0xF, false)); // wave_shr1
}
// LDS-only barrier (no vmcnt drain). 0xC07F = vmcnt(63) expcnt(7) lgkmcnt(0).
__device__ __forceinline__ void barrier_lds() {
    __asm__ __volatile__("" ::: "memory");
    __builtin_amdgcn_s_waitcnt(0xC07F);
    __builtin_amdgcn_s_barrier();
    __asm__ __volatile__("" ::: "memory");
}

__global__ __launch_bounds__(192)
void dtw_fwd_kernel(const float* __restrict__ input,
                    const float* __restrict__ target,
                    float* __restrict__ sdtw,    // BC_TOT: R[N,N]
                    float* __restrict__ wlt)     // BC_TOT: Rdot[N,N]/N^2
{
    const int kA   = 2 * blockIdx.x;             // problems kA, kA+1
    const int tid  = threadIdx.x;
    const int w    = tid >> 6;
    const int lane = tid & 63;
    const bool rowok = (tid < NN);

    __shared__ __align__(16) float  Pp[2][4][520]; // [prob][replica s][y]
    __shared__ __align__(16) float4 bRG[2][RSZ];   // ring: (rA,gA,rB,gB) @ diag

    const float* tgA = target + (size_t)kA * NN;
    const float* pgA = input  + (size_t)kA * NN;
    const float* tgB = tgA + NN;
    const float* pgB = pgA + NN;
    // V(z) = P[z-192]*SC2 for z in [192,352), else 0
    for (int x = tid; x < 520; x += 192) {
        #pragma unroll
        for (int s = 0; s < 4; ++s) {
            const int v = x + s - 192;
            const bool ok = ((unsigned)v < (unsigned)NN);
            Pp[0][s][x] = ok ? pgA[v] * SC2 : 0.0f;
            Pp[1][s][x] = ok ? pgB[v] * SC2 : 0.0f;
        }
    }
    for (int x = tid; x < 2 * RSZ; x += 192) {
        float4 z; z.x = BIGC2; z.y = 0.0f; z.z = BIGC2; z.w = 0.0f;
        ((float4*)bRG)[x] = z;                   // unwritten slot == true border
    }
    const float trA = rowok ? tgA[tid] * SC2 : 0.0f;
    const float trB = rowok ? tgB[tid] * SC2 : 0.0f;
    barrier_lds();

    const bool isL0    = (lane == 0);
    const bool isL63p  = (lane == 63) && (w < 2);
    const bool useRing = (w > 0);
    const int  ti2     = 2 * (tid + 1);          // 2*i

    // Wave w active chunks: [4w, min(19, 4w+13)]
    const int cLoF = 4 * w;
    const int cHiF = (4 * w + 13 < NCHUNK - 1) ? 4 * w + 13 : NCHUNK - 1;

    // rolling state (C2 domain), duplicated for problems A and B.
    float r1A = BIGC2, u1A = BIGC2, u2A = BIGC2;
    float s1A = 0.0f,  v1A = 0.0f,  v2A = 0.0f;
    float r1B = BIGC2, u1B = BIGC2, u2B = BIGC2;
    float s1B = 0.0f,  v1B = 0.0f,  v2B = 0.0f;

    for (int t = 0; t < NPHASE; ++t) {
        const int c = t - w;
        if (c >= cLoF && c <= cHiF) {
            const int dlo = 2 + c * KPH;
            // ring window slots [dlo-2, dlo+15] (18): b128 broadcast reads
            float rgxA[18], rgdA[18], rgxB[18], rgdB[18];
            if (useRing) {
                const float4* q = &bRG[w - 1][dlo - 2];
                #pragma unroll
                for (int x = 0; x < 18; ++x) {
                    const float4 v4 = q[x];
                    rgxA[x] = v4.x; rgdA[x] = v4.y;
                    rgxB[x] = v4.z; rgdB[x] = v4.w;
                }
            } else {
                #pragma unroll
                for (int x = 0; x < 18; ++x) {
                    rgxA[x] = BIGC2; rgdA[x] = 0.0f;
                    rgxB[x] = BIGC2; rgdB[x] = 0.0f;
                }
                if (c == 0) { rgxA[0] = 0.0f; rgxB[0] = 0.0f; } // R[0][0]=0 @ d=2
            }
            // P windows (pre-scaled), aligned replica reads
            float pvvA[KPH], pvvB[KPH];
            {
                const int A  = 192 - tid + KPH * c;
                const int sA = A & 3;
                const float4* qa = (const float4*)&Pp[0][sA][A - sA];
                const float4* qb = (const float4*)&Pp[1][sA][A - sA];
                #pragma unroll
                for (int x = 0; x < 4; ++x) {
                    const float4 a4 = qa[x];
                    const float4 b4 = qb[x];
                    pvvA[4 * x]     = a4.x; pvvA[4 * x + 1] = a4.y;
                    pvvA[4 * x + 2] = a4.z; pvvA[4 * x + 3] = a4.w;
                    pvvB[4 * x]     = b4.x; pvvB[4 * x + 1] = b4.y;
                    pvvB[4 * x + 2] = b4.z; pvvB[4 * x + 3] = b4.w;
                }
            }
            if (c == cLoF) {     // one-time boundary injection (first chunk)
                u1A = isL0 ? rgxA[1] : BIGC2;  u2A = isL0 ? rgxA[0] : BIGC2;
                v1A = isL0 ? rgdA[1] : 0.0f;   v2A = isL0 ? rgdA[0] : 0.0f;
                u1B = isL0 ? rgxB[1] : BIGC2;  u2B = isL0 ? rgxB[0] : BIGC2;
                v1B = isL0 ? rgdB[1] : 0.0f;   v2B = isL0 ? rgdB[0] : 0.0f;
            }
            float djf = (float)(dlo - ti2);      // j - i at u=0
            #pragma unroll
            for (int u = 0; u < KPH; ++u) {
                const int d = dlo + u;           // d=321 pad step: harmless
                const float om = djf * djf;      // Omega shared by A and B
                // ---- problem A (op order identical to r12) ----
                const float mnA = fminf(u2A, fminf(u1A, r1A));
                const float edA = fexp2(mnA - u2A);   // SUBTRACT form (r5 rule)
                const float evA = fexp2(mnA - u1A);
                const float ehA = fexp2(mnA - r1A);
                const float ssA = edA + evA + ehA;    // >= 1
                const float rsA = frcp(ssA);
                const float dtA = trA - pvvA[u];
                const float rCA = __builtin_fmaf(dtA, dtA, mnA) - flog2(ssA);
                const float numA = __builtin_fmaf(edA, v2A,
                                   __builtin_fmaf(evA, v1A, ehA * s1A));
                const float rdA = __builtin_fmaf(numA, rsA, om);
                // ---- problem B ----
                const float mnB = fminf(u2B, fminf(u1B, r1B));
                const float edB = fexp2(mnB - u2B);
                const float evB = fexp2(mnB - u1B);
                const float ehB = fexp2(mnB - r1B);
                const float ssB = edB + evB + ehB;
                const float rsB = frcp(ssB);
                const float dtB = trB - pvvB[u];
                const float rCB = __builtin_fmaf(dtB, dtB, mnB) - flog2(ssB);
                const float numB = __builtin_fmaf(edB, v2B,
                                   __builtin_fmaf(evB, v1B, ehB * s1B));
                const float rdB = __builtin_fmaf(numB, rsB, om);

                if (isL63p) {                    // single b128 publish, both probs
                    float4 pub;
                    pub.x = rCA; pub.y = rdA; pub.z = rCB; pub.w = rdB;
                    bRG[w][d] = pub;
                }
                if (d == 2 * NN) {
                    if (tid == NN - 1) {         // cell (160,160), both problems
                        sdtw[kA]     = rCA * GLN2;
                        wlt[kA]      = rdA * (1.0f / (NN * NN));
                        sdtw[kA + 1] = rCB * GLN2;
                        wlt[kA + 1]  = rdB * (1.0f / (NN * NN));
                    }
                }
                u2A = u1A; u1A = dpp_up1_inj(rgxA[u + 2], rCA);  // lane0 <- slot d
                v2A = v1A; v1A = dpp_up1_inj(rgdA[u + 2], rdA);
                r1A = rCA; s1A = rdA;
                u2B = u1B; u1B = dpp_up1_inj(rgxB[u + 2], rCB);
                v2B = v1B; v1B = dpp_up1_inj(rgdB[u + 2], rdB);
                r1B = rCB; s1B = rdB;
                djf += 1.0f;
            }
        }
        barrier_lds();
    }
}

// final reduction: per-batch means + scalar loss. One wave (64 threads = B).
__global__ __launch_bounds__(64)
void finalize_kernel(const float* __restrict__ sdtw,
                     const float* __restrict__ wlt,
                     float* __restrict__ out)
{
    const int b = threadIdx.x;   // 0..63
    float ls = 0.0f, lt = 0.0f;
    #pragma unroll
    for (int c = 0; c < C_SZ; ++c) {
        ls += sdtw[b * C_SZ + c];
        lt += wlt[b * C_SZ + c];
    }
    ls *= (1.0f / C_SZ);
    lt *= (1.0f / C_SZ);
    out[1 + b]        = ls;
    out[1 + B_SZ + b] = lt;
    float v = 0.5f * ls + 0.5f * lt;
    #pragma unroll
    for (int o = 32; o > 0; o >>= 1) v += __shfl_down(v, o);
    if (b == 0) out[0] = v * (1.0f / B_SZ);
}

extern "C" void kernel_launch(void* const* d_in, const int* in_sizes, int n_in,
                              void* d_out, int out_size, void* d_ws, size_t ws_size,
                              hipStream_t stream) {
    const float* input  = (const float*)d_in[0];
    const float* target = (const float*)d_in[1];
    float* out = (float*)d_out;   // 129 floats

    float* sdtw = (float*)d_ws;                 // 512 floats
    float* wlt  = sdtw + BC_TOT;                // 512 floats

    dtw_fwd_kernel<<<BC_TOT / 2, 192, 0, stream>>>(input, target, sdtw, wlt);
    finalize_kernel<<<1, 64, 0, stream>>>(sdtw, wlt, out);
}